// Round 2
// baseline (1117.929 us; speedup 1.0000x reference)
//
#include <hip/hip_runtime.h>
#include <math.h>

// ---- problem constants ----
#define CC   128
#define PP   256
#define NHH  8
#define HDD  32
#define HIDD 384
#define LL   196
#define NWW  128
#define BNN  256          // B*NW
#define TT   50176        // BNN*LL
#define DV   8
#define HV   56
#define WV   56

typedef __attribute__((ext_vector_type(8))) short short8;
typedef __attribute__((ext_vector_type(4))) float f32x4;

// packed split-weight layout (shorts), hi plane then lo plane at +WT_TOTAL
#define WT_OQ 0
#define WT_OK 32768
#define WT_OV 65536
#define WT_OO 98304
#define WT_O1 131072
#define WT_O2 180224
#define WT_TOTAL 229376

__device__ __forceinline__ unsigned short f2bf(float x){
    unsigned u = __float_as_uint(x);
    u += 0x7FFFu + ((u >> 16) & 1u);          // round-to-nearest-even
    return (unsigned short)(u >> 16);
}
__device__ __forceinline__ float bf2f(unsigned short h){
    return __uint_as_float(((unsigned)h) << 16);
}
__device__ __forceinline__ int pack2(unsigned short a, unsigned short b){
    return (int)(unsigned)a | ((int)(unsigned)b << 16);
}

// =====================================================================
// K-1: transpose + split all weights into bf16 hi/lo planes.
// dst is col-major-per-matrix: [n][k] so MFMA B-frags read contiguous k.
// =====================================================================
__global__ __launch_bounds__(256) void k_wprep(
    const float* __restrict__ Wq, const float* __restrict__ Wk, const float* __restrict__ Wv,
    const float* __restrict__ Wo, const float* __restrict__ W1, const float* __restrict__ W2,
    short* __restrict__ WT)
{
    int t = blockIdx.x * 256 + threadIdx.x;
    if (t >= WT_TOTAL) return;
    float v;
    if (t < WT_OO) {                   // Wq/Wk/Wv: dst [n<256][k<128]
        int mat = t >> 15;
        int r = t & 32767;
        int n = r >> 7, kk = r & 127;
        const float* s = (mat == 0) ? Wq : (mat == 1) ? Wk : Wv;
        v = s[kk * PP + n];
    } else if (t < WT_O1) {            // Wo: dst [n<128][k<256]
        int r = t - WT_OO;
        int n = r >> 8, kk = r & 255;
        v = Wo[kk * CC + n];
    } else if (t < WT_O2) {            // W1: dst [n<384][k<128]
        int r = t - WT_O1;
        int n = r >> 7, kk = r & 127;
        v = W1[kk * HIDD + n];
    } else {                           // W2: dst [n<128][k<384]
        int r = t - WT_O2;
        int n = r / 384, kk = r - n * 384;
        v = W2[kk * CC + n];
    }
    unsigned short h = f2bf(v);
    float lo = v - bf2f(h);
    WT[t] = (short)h;
    WT[WT_TOTAL + t] = (short)f2bf(lo);
}

// =====================================================================
// K0: biasT[h][j][i] = rel_table[rel_idx[i][j]*NH + h]
// =====================================================================
__global__ __launch_bounds__(256) void k_bias(const float* __restrict__ tbl,
                                              const int* __restrict__ idx,
                                              float* __restrict__ biasT) {
    int t = blockIdx.x * 256 + threadIdx.x;
    if (t >= NHH * LL * LL) return;
    int i = t % LL;
    int j = (t / LL) % LL;
    int h = t / (LL * LL);
    biasT[t] = tbl[idx[i * LL + j] * NHH + h];
}

// =====================================================================
// split-bf16 MFMA GEMM: Y[M][ND] = X[M][KD] @ W + b   (3 mfma / product)
// tile 128x128, 4 waves of 64x64, 16x16x32 bf16 MFMA.
// QKV mode: A rows gathered via roll+partition offsets; Y head-major;
// z==0,y==0 blocks also write the residual copy of gathered q.
// =====================================================================
template<int KD, int ND, int GELU, int QKV>
__global__ __launch_bounds__(256) void k_mgemm(
    const float* __restrict__ X0, const float* __restrict__ X1, const float* __restrict__ X2,
    const short* __restrict__ WhB, const short* __restrict__ WlB,
    const float* __restrict__ bb0, const float* __restrict__ bb1, const float* __restrict__ bb2,
    float* __restrict__ Y0, float* __restrict__ Y1, float* __restrict__ Y2,
    float* __restrict__ resid)
{
    __shared__ __align__(16) short Ah[128][40];   // [row][k], +8 pad: 2-way-free banks
    __shared__ __align__(16) short Al[128][40];
    __shared__ __align__(16) short Bh[128][40];   // [col][k]
    __shared__ __align__(16) short Bl[128][40];
    __shared__ int s_off[128];

    const int tid = threadIdx.x;
    const int m0 = blockIdx.x * 128;
    const int c0 = blockIdx.y * 128;
    const int z = QKV ? blockIdx.z : 0;
    const float* __restrict__ X  = (z == 0) ? X0 : (z == 1) ? X1 : X2;
    const float* __restrict__ bb = (z == 0) ? bb0 : (z == 1) ? bb1 : bb2;
    float* __restrict__ Y        = (z == 0) ? Y0 : (z == 1) ? Y1 : Y2;
    const short* __restrict__ Wh = WhB + (QKV ? z * 32768 : 0);
    const short* __restrict__ Wl = WlB + (QKV ? z * 32768 : 0);

    if (QKV && tid < 128) {
        int m = m0 + tid;
        int l = m % LL, bw = m / LL;
        int w = bw & (NWW - 1), b = bw >> 7;
        int wd = w >> 6, wh = (w >> 3) & 7, ww = w & 7;
        int td = l / 49, r = l % 49, th = r / 7, tw = r % 7;
        int d  = wd * 4 + td + 2;  if (d  >= DV) d  -= DV;
        int hh = wh * 7 + th + 3;  if (hh >= HV) hh -= HV;
        int wc2 = ww * 7 + tw + 3; if (wc2 >= WV) wc2 -= WV;
        s_off[tid] = (((b * DV + d) * HV + hh) * WV + wc2) * CC;
    }

    const int wid = tid >> 6, lane = tid & 63;
    const int wr = wid >> 1, wc = wid & 1;
    const int lrow = lane & 15, kg = lane >> 4;

    f32x4 acc[4][4];
    f32x4 zero = {0.f, 0.f, 0.f, 0.f};
#pragma unroll
    for (int m = 0; m < 4; m++)
#pragma unroll
        for (int n = 0; n < 4; n++) acc[m][n] = zero;

    const int arow = tid >> 1, ahalf = tid & 1;

    for (int kc = 0; kc < KD / 32; kc++) {
        __syncthreads();
        {   // ---- stage A (fp32 -> split bf16) ----
            const float* gp;
            if (QKV) gp = X + s_off[arow] + kc * 32 + ahalf * 16;
            else     gp = X + (size_t)(m0 + arow) * KD + kc * 32 + ahalf * 16;
            float4 a0 = *(const float4*)(gp);
            float4 a1 = *(const float4*)(gp + 4);
            float4 a2 = *(const float4*)(gp + 8);
            float4 a3 = *(const float4*)(gp + 12);
            if (QKV && z == 0 && blockIdx.y == 0) {
                float* rp = resid + (size_t)(m0 + arow) * CC + kc * 32 + ahalf * 16;
                *(float4*)(rp) = a0; *(float4*)(rp + 4) = a1;
                *(float4*)(rp + 8) = a2; *(float4*)(rp + 12) = a3;
            }
            float f[16] = {a0.x,a0.y,a0.z,a0.w, a1.x,a1.y,a1.z,a1.w,
                           a2.x,a2.y,a2.z,a2.w, a3.x,a3.y,a3.z,a3.w};
            int hi[8], lo[8];
#pragma unroll
            for (int e = 0; e < 8; e++) {
                unsigned short h0 = f2bf(f[2*e]),   h1 = f2bf(f[2*e+1]);
                float l0 = f[2*e] - bf2f(h0), l1 = f[2*e+1] - bf2f(h1);
                hi[e] = pack2(h0, h1);
                lo[e] = pack2(f2bf(l0), f2bf(l1));
            }
            int4* dh = (int4*)&Ah[arow][ahalf * 16];
            dh[0] = make_int4(hi[0], hi[1], hi[2], hi[3]);
            dh[1] = make_int4(hi[4], hi[5], hi[6], hi[7]);
            int4* dl = (int4*)&Al[arow][ahalf * 16];
            dl[0] = make_int4(lo[0], lo[1], lo[2], lo[3]);
            dl[1] = make_int4(lo[4], lo[5], lo[6], lo[7]);
        }
        {   // ---- stage B (pre-split, straight copy) ----
            const short* sh = Wh + (size_t)(c0 + arow) * KD + kc * 32 + ahalf * 16;
            const short* sl = Wl + (size_t)(c0 + arow) * KD + kc * 32 + ahalf * 16;
            int4* dh = (int4*)&Bh[arow][ahalf * 16];
            dh[0] = *(const int4*)(sh); dh[1] = *(const int4*)(sh + 8);
            int4* dl = (int4*)&Bl[arow][ahalf * 16];
            dl[0] = *(const int4*)(sl); dl[1] = *(const int4*)(sl + 8);
        }
        __syncthreads();

        short8 afh[4], afl[4], bfh[4], bfl[4];
#pragma unroll
        for (int m = 0; m < 4; m++) {
            int r = wr * 64 + m * 16 + lrow;
            afh[m] = *(const short8*)&Ah[r][kg * 8];
            afl[m] = *(const short8*)&Al[r][kg * 8];
        }
#pragma unroll
        for (int n = 0; n < 4; n++) {
            int cidx = wc * 64 + n * 16 + lrow;
            bfh[n] = *(const short8*)&Bh[cidx][kg * 8];
            bfl[n] = *(const short8*)&Bl[cidx][kg * 8];
        }
#pragma unroll
        for (int m = 0; m < 4; m++)
#pragma unroll
            for (int n = 0; n < 4; n++) {
                acc[m][n] = __builtin_amdgcn_mfma_f32_16x16x32_bf16(afh[m], bfh[n], acc[m][n], 0, 0, 0);
                acc[m][n] = __builtin_amdgcn_mfma_f32_16x16x32_bf16(afh[m], bfl[n], acc[m][n], 0, 0, 0);
                acc[m][n] = __builtin_amdgcn_mfma_f32_16x16x32_bf16(afl[m], bfh[n], acc[m][n], 0, 0, 0);
            }
    }

    // ---- epilogue: +bias (opt GELU), store ----
#pragma unroll
    for (int n = 0; n < 4; n++) {
        int col = c0 + wc * 64 + n * 16 + lrow;
        float bv = bb[col];
#pragma unroll
        for (int m = 0; m < 4; m++) {
#pragma unroll
            for (int rg = 0; rg < 4; rg++) {
                int r = wr * 64 + m * 16 + kg * 4 + rg;   // C/D: row=(lane>>4)*4+reg
                float x = acc[m][n][rg] + bv;
                if (GELU) x = 0.5f * x * (1.f + erff(x * 0.70710678118654752f));
                int tok = m0 + r;
                if (QKV) {
                    int bw = (unsigned)tok / LL;
                    int l  = tok - bw * LL;
                    int head = col >> 5, hd = col & 31;
                    Y[(((size_t)bw * NHH + head) * LL + l) * HDD + hd] = x;
                } else {
                    Y[(size_t)tok * ND + col] = x;
                }
            }
        }
    }
}

// =====================================================================
// K2: attention. K/V rows are wave-uniform -> stream from L2 into regs
// (double-buffered), zero LDS. One q-row per lane.
// =====================================================================
__global__ __launch_bounds__(256) void k_attn(
    const float* __restrict__ Qh, const float* __restrict__ Kh, const float* __restrict__ Vh,
    const float* __restrict__ biasT, const float* __restrict__ mask, float* __restrict__ ctx)
{
    const int h = blockIdx.x, bn = blockIdx.y;
    const int i = threadIdx.x;
    if (i >= LL) return;
    const size_t base = ((size_t)bn * NHH + h) * (LL * HDD);
    const float* __restrict__ kb = Kh + base;
    const float* __restrict__ vb = Vh + base;

    float4 qv[8], cv[8];
    {
        const float4* qp = (const float4*)(Qh + base + (size_t)i * HDD);
#pragma unroll
        for (int u = 0; u < 8; u++) { qv[u] = qp[u]; cv[u] = make_float4(0.f, 0.f, 0.f, 0.f); }
    }
    const float* bs = biasT + (size_t)h * LL * LL + i;
    const float* ms = mask + (size_t)(bn & (NWW - 1)) * LL * LL + i;

    float4 kA[8], vA[8], kB[8], vB[8];
#pragma unroll
    for (int u = 0; u < 8; u++) { kA[u] = *(const float4*)(kb + u*4); vA[u] = *(const float4*)(vb + u*4); }

    float ssum = 0.f;
    for (int j = 0; j < LL; j += 2) {
        {   // prefetch row j+1 (always valid: LL even)
            const float* kp = kb + (size_t)(j + 1) * HDD;
            const float* vp = vb + (size_t)(j + 1) * HDD;
#pragma unroll
            for (int u = 0; u < 8; u++) { kB[u] = *(const float4*)(kp + u*4); vB[u] = *(const float4*)(vp + u*4); }
        }
        {   // compute row j with A regs
            float dacc = 0.f;
#pragma unroll
            for (int u = 0; u < 8; u++)
                dacc += qv[u].x*kA[u].x + qv[u].y*kA[u].y + qv[u].z*kA[u].z + qv[u].w*kA[u].w;
            float p = __expf(dacc * 0.17677669529663687f + bs[(size_t)j * LL] + ms[(size_t)j * LL]);
            ssum += p;
#pragma unroll
            for (int u = 0; u < 8; u++) {
                cv[u].x += p * vA[u].x; cv[u].y += p * vA[u].y;
                cv[u].z += p * vA[u].z; cv[u].w += p * vA[u].w;
            }
        }
        if (j + 2 < LL) {   // prefetch row j+2 into A
            const float* kp = kb + (size_t)(j + 2) * HDD;
            const float* vp = vb + (size_t)(j + 2) * HDD;
#pragma unroll
            for (int u = 0; u < 8; u++) { kA[u] = *(const float4*)(kp + u*4); vA[u] = *(const float4*)(vp + u*4); }
        }
        {   // compute row j+1 with B regs
            float dacc = 0.f;
#pragma unroll
            for (int u = 0; u < 8; u++)
                dacc += qv[u].x*kB[u].x + qv[u].y*kB[u].y + qv[u].z*kB[u].z + qv[u].w*kB[u].w;
            float p = __expf(dacc * 0.17677669529663687f + bs[(size_t)(j+1) * LL] + ms[(size_t)(j+1) * LL]);
            ssum += p;
#pragma unroll
            for (int u = 0; u < 8; u++) {
                cv[u].x += p * vB[u].x; cv[u].y += p * vB[u].y;
                cv[u].z += p * vB[u].z; cv[u].w += p * vB[u].w;
            }
        }
    }
    float inv = 1.f / ssum;
    float4* op = (float4*)(ctx + ((size_t)bn * LL + i) * PP + h * HDD);
#pragma unroll
    for (int u = 0; u < 8; u++) {
        float4 r; r.x = cv[u].x*inv; r.y = cv[u].y*inv; r.z = cv[u].z*inv; r.w = cv[u].w*inv;
        op[u] = r;
    }
}

// =====================================================================
// LN (+residual add).  One wave per row of 128.
// =====================================================================
__global__ __launch_bounds__(256) void k_ln_add(
    const float* __restrict__ X, const float* __restrict__ gg, const float* __restrict__ bb,
    const float* __restrict__ res, float* __restrict__ Y)
{
    const int row = blockIdx.x * 4 + (threadIdx.x >> 6);
    const int lane = threadIdx.x & 63;
    const float2 v = ((const float2*)(X + (size_t)row * CC))[lane];
    float s = v.x + v.y, s2 = v.x * v.x + v.y * v.y;
#pragma unroll
    for (int m = 1; m < 64; m <<= 1) { s += __shfl_xor(s, m); s2 += __shfl_xor(s2, m); }
    const float mean = s * 0.0078125f;
    const float var  = s2 * 0.0078125f - mean * mean;
    const float rinv = rsqrtf(var + 1e-5f);
    const float2 g2 = ((const float2*)gg)[lane];
    const float2 b2 = ((const float2*)bb)[lane];
    const float2 r2 = ((const float2*)(res + (size_t)row * CC))[lane];
    float2 o;
    o.x = (v.x - mean) * rinv * g2.x + b2.x + r2.x;
    o.y = (v.y - mean) * rinv * g2.y + b2.y + r2.y;
    ((float2*)(Y + (size_t)row * CC))[lane] = o;
}

// =====================================================================
// LN2 + residual + reverse-partition + roll(+2,+3,+3) scatter to output
// =====================================================================
__global__ __launch_bounds__(256) void k_ln2_scatter(
    const float* __restrict__ X, const float* __restrict__ gg, const float* __restrict__ bb,
    const float* __restrict__ res, float* __restrict__ out)
{
    const int row = blockIdx.x * 4 + (threadIdx.x >> 6);
    const int lane = threadIdx.x & 63;
    const float2 v = ((const float2*)(X + (size_t)row * CC))[lane];
    float s = v.x + v.y, s2 = v.x * v.x + v.y * v.y;
#pragma unroll
    for (int m = 1; m < 64; m <<= 1) { s += __shfl_xor(s, m); s2 += __shfl_xor(s2, m); }
    const float mean = s * 0.0078125f;
    const float var  = s2 * 0.0078125f - mean * mean;
    const float rinv = rsqrtf(var + 1e-5f);
    const float2 g2 = ((const float2*)gg)[lane];
    const float2 b2 = ((const float2*)bb)[lane];
    const float2 r2 = ((const float2*)(res + (size_t)row * CC))[lane];
    float2 o;
    o.x = (v.x - mean) * rinv * g2.x + b2.x + r2.x;
    o.y = (v.y - mean) * rinv * g2.y + b2.y + r2.y;

    int l = row % LL, bw = row / LL;
    int w = bw & (NWW - 1), b = bw >> 7;
    int wd = w >> 6, wh = (w >> 3) & 7, ww = w & 7;
    int td = l / 49, r = l % 49, th = r / 7, tw = r % 7;
    int d  = wd * 4 + td + 2;  if (d  >= DV) d  -= DV;
    int hh = wh * 7 + th + 3;  if (hh >= HV) hh -= HV;
    int wc = ww * 7 + tw + 3;  if (wc >= WV) wc -= WV;
    size_t dest = (((size_t)(b * DV + d) * HV + hh) * WV + wc) * CC;
    ((float2*)(out + dest))[lane] = o;
}

// =====================================================================
extern "C" void kernel_launch(void* const* d_in, const int* in_sizes, int n_in,
                              void* d_out, int out_size, void* d_ws, size_t ws_size,
                              hipStream_t stream)
{
    (void)in_sizes; (void)n_in; (void)out_size;
    const float* q    = (const float*)d_in[0];
    const float* k    = (const float*)d_in[1];
    const float* v    = (const float*)d_in[2];
    const float* Wq   = (const float*)d_in[3];
    const float* bq   = (const float*)d_in[4];
    const float* Wk   = (const float*)d_in[5];
    const float* bk   = (const float*)d_in[6];
    const float* Wv   = (const float*)d_in[7];
    const float* bv   = (const float*)d_in[8];
    const float* Wo   = (const float*)d_in[9];
    const float* bo   = (const float*)d_in[10];
    const float* rtab = (const float*)d_in[11];
    const float* g1   = (const float*)d_in[12];
    const float* b1n  = (const float*)d_in[13];
    const float* W1   = (const float*)d_in[14];
    const float* b1m  = (const float*)d_in[15];
    const float* W2   = (const float*)d_in[16];
    const float* b2m  = (const float*)d_in[17];
    const float* g2   = (const float*)d_in[18];
    const float* b2n  = (const float*)d_in[19];
    const int*   ridx = (const int*)d_in[20];
    const float* msk  = (const float*)d_in[21];
    float* out = (float*)d_out;
    float* ws  = (float*)d_ws;

    const size_t TC = (size_t)TT * CC;
    const size_t TP = (size_t)TT * PP;
    const size_t BIAS = (size_t)NHH * LL * LL;

    float* resid = ws;                 // [T][C]
    float* Qb    = ws + TC;            // [Bn][NH][L][HD]
    float* Kb    = Qb + TP;
    float* Vb    = Kb + TP;
    float* ctxb  = Vb + TP;            // [Bn][L][P]
    float* biasT = ctxb + TP;          // [NH][L][L]
    float* proj1 = Qb;                 // [T][C]   (Q dead after attn)
    float* h2    = Qb + TC;            // [T][C]
    float* attnb = Kb;                 // [T][C]   (K dead after attn)
    float* h1    = Vb;                 // [T][HID] (V+ctx dead)

    // split weights live in d_out's space; the final scatter fully
    // overwrites d_out afterwards.
    short* WT = (short*)d_out;

    const size_t need = (TC + 4 * TP + BIAS) * sizeof(float);
    if (ws_size < need) return;

    k_wprep<<<dim3(WT_TOTAL / 256), dim3(256), 0, stream>>>(Wq, Wk, Wv, Wo, W1, W2, WT);
    k_bias<<<dim3((NHH * LL * LL + 255) / 256), dim3(256), 0, stream>>>(rtab, ridx, biasT);

    k_mgemm<128, 256, 0, 1><<<dim3(TT / 128, 2, 3), dim3(256), 0, stream>>>(
        q, k, v, WT + WT_OQ, WT + WT_TOTAL + WT_OQ,
        bq, bk, bv, Qb, Kb, Vb, resid);

    k_attn<<<dim3(NHH, BNN), dim3(256), 0, stream>>>(Qb, Kb, Vb, biasT, msk, ctxb);

    k_mgemm<256, 128, 0, 0><<<dim3(TT / 128, 1), dim3(256), 0, stream>>>(
        ctxb, ctxb, ctxb, WT + WT_OO, WT + WT_TOTAL + WT_OO,
        bo, bo, bo, proj1, proj1, proj1, nullptr);

    k_ln_add<<<dim3(TT / 4), dim3(256), 0, stream>>>(proj1, g1, b1n, resid, attnb);

    k_mgemm<128, 384, 1, 0><<<dim3(TT / 128, 3), dim3(256), 0, stream>>>(
        attnb, attnb, attnb, WT + WT_O1, WT + WT_TOTAL + WT_O1,
        b1m, b1m, b1m, h1, h1, h1, nullptr);

    k_mgemm<384, 128, 0, 0><<<dim3(TT / 128, 1), dim3(256), 0, stream>>>(
        h1, h1, h1, WT + WT_O2, WT + WT_TOTAL + WT_O2,
        b2m, b2m, b2m, h2, h2, h2, nullptr);

    k_ln2_scatter<<<dim3(TT / 4), dim3(256), 0, stream>>>(h2, g2, b2n, attnb, out);
}

// Round 3
// 450.459 us; speedup vs baseline: 2.4818x; 2.4818x over previous
//
#include <hip/hip_runtime.h>
#include <math.h>

// ---- problem constants ----
#define CC   128
#define PP   256
#define NHH  8
#define HDD  32
#define HIDD 384
#define LL   196
#define NWW  128
#define BNN  256          // B*NW
#define TT   50176        // BNN*LL
#define DV   8
#define HV   56
#define WV   56
#define KPAD 224          // padded token count (14*16)
#define QPAD 224

typedef __attribute__((ext_vector_type(8))) short short8;
typedef __attribute__((ext_vector_type(4))) float f32x4;

// packed split-weight layout (shorts), hi plane then lo plane at +WT_TOTAL
#define WT_OQ 0
#define WT_OK 32768
#define WT_OV 65536
#define WT_OO 98304
#define WT_O1 131072
#define WT_O2 180224
#define WT_TOTAL 229376

__device__ __forceinline__ unsigned short f2bf(float x){
    unsigned u = __float_as_uint(x);
    u += 0x7FFFu + ((u >> 16) & 1u);          // round-to-nearest-even
    return (unsigned short)(u >> 16);
}
__device__ __forceinline__ float bf2f(unsigned short h){
    return __uint_as_float(((unsigned)h) << 16);
}
__device__ __forceinline__ int pack2(unsigned short a, unsigned short b){
    return (int)(unsigned)a | ((int)(unsigned)b << 16);
}

// =====================================================================
// weight prep: transpose + split into bf16 hi/lo planes, dst [n][k]
// =====================================================================
__global__ __launch_bounds__(256) void k_wprep(
    const float* __restrict__ Wq, const float* __restrict__ Wk, const float* __restrict__ Wv,
    const float* __restrict__ Wo, const float* __restrict__ W1, const float* __restrict__ W2,
    short* __restrict__ WT)
{
    int t = blockIdx.x * 256 + threadIdx.x;
    if (t >= WT_TOTAL) return;
    float v;
    if (t < WT_OO) {                   // Wq/Wk/Wv: dst [n<256][k<128]
        int mat = t >> 15;
        int r = t & 32767;
        int n = r >> 7, kk = r & 127;
        const float* s = (mat == 0) ? Wq : (mat == 1) ? Wk : Wv;
        v = s[kk * PP + n];
    } else if (t < WT_O1) {            // Wo: dst [n<128][k<256]
        int r = t - WT_OO;
        int n = r >> 8, kk = r & 255;
        v = Wo[kk * CC + n];
    } else if (t < WT_O2) {            // W1: dst [n<384][k<128]
        int r = t - WT_O1;
        int n = r >> 7, kk = r & 127;
        v = W1[kk * HIDD + n];
    } else {                           // W2: dst [n<128][k<384]
        int r = t - WT_O2;
        int n = r / 384, kk = r - n * 384;
        v = W2[kk * CC + n];
    }
    unsigned short h = f2bf(v);
    float lo = v - bf2f(h);
    WT[t] = (short)h;
    WT[WT_TOTAL + t] = (short)f2bf(lo);
}

// =====================================================================
// padded bf16 tables: biasM[h][q<224][k<224], maskM[w][q<224][k<224]
// pad k/q >=196: bias -> -1e4 (forces p==0), mask -> 0
// =====================================================================
__global__ __launch_bounds__(256) void k_tab(const float* __restrict__ tbl,
                                             const int* __restrict__ idx,
                                             short* __restrict__ biasM)
{
    int t = blockIdx.x * 256 + threadIdx.x;
    if (t >= NHH * QPAD * KPAD) return;
    int k = t % KPAD, q = (t / KPAD) % QPAD, h = t / (KPAD * QPAD);
    float v = (q < LL && k < LL) ? tbl[idx[q * LL + k] * NHH + h] : -1.0e4f;
    biasM[t] = (short)f2bf(v);
}

__global__ __launch_bounds__(256) void k_maskpad(const float* __restrict__ msk,
                                                 short* __restrict__ maskM)
{
    int t = blockIdx.x * 256 + threadIdx.x;
    if (t >= NWW * QPAD * KPAD) return;
    int k = t % KPAD, q = (t / KPAD) % QPAD, w = t / (KPAD * QPAD);
    float v = (q < LL && k < LL) ? msk[(size_t)w * LL * LL + q * LL + k] : 0.f;
    maskM[t] = (short)f2bf(v);
}

// =====================================================================
// split-bf16 MFMA GEMM.  tile 128x128, 4 waves of 64x64, 16x16x32 MFMA.
// QKV mode: A rows gathered via roll+partition; outputs bf16 head-major
// (z<2) or transposed Vt[bn][h][d][224] (z==2); z==0,y==0 writes resid.
// ASRC_BF16: A input is bf16 [T][KD] (2 mfma/product instead of 3).
// AOUT_BF16: Y is bf16 [T][ND].
// =====================================================================
template<int KD, int ND, int GELU, int QKV, int ASRC_BF16, int AOUT_BF16>
__global__ __launch_bounds__(256) void k_mgemm(
    const void* __restrict__ X0, const void* __restrict__ X1, const void* __restrict__ X2,
    const short* __restrict__ WhB, const short* __restrict__ WlB,
    const float* __restrict__ bb0, const float* __restrict__ bb1, const float* __restrict__ bb2,
    void* __restrict__ Y0, void* __restrict__ Y1, void* __restrict__ Y2,
    float* __restrict__ resid)
{
    __shared__ __align__(16) short Ah[128][40];
    __shared__ __align__(16) short Al[128][40];
    __shared__ __align__(16) short Bh[128][40];
    __shared__ __align__(16) short Bl[128][40];
    __shared__ int s_off[128];

    const int tid = threadIdx.x;
    const int m0 = blockIdx.x * 128;
    const int c0 = blockIdx.y * 128;
    const int z = QKV ? blockIdx.z : 0;
    const void* __restrict__ X  = (z == 0) ? X0 : (z == 1) ? X1 : X2;
    const float* __restrict__ bb = (z == 0) ? bb0 : (z == 1) ? bb1 : bb2;
    void* __restrict__ Y         = (z == 0) ? Y0 : (z == 1) ? Y1 : Y2;
    const short* __restrict__ Wh = WhB + (QKV ? z * 32768 : 0);
    const short* __restrict__ Wl = WlB + (QKV ? z * 32768 : 0);

    if (QKV && tid < 128) {
        int m = m0 + tid;
        int l = m % LL, bw = m / LL;
        int w = bw & (NWW - 1), b = bw >> 7;
        int wd = w >> 6, wh = (w >> 3) & 7, ww = w & 7;
        int td = l / 49, r = l % 49, th = r / 7, tw = r % 7;
        int d  = wd * 4 + td + 2;  if (d  >= DV) d  -= DV;
        int hh = wh * 7 + th + 3;  if (hh >= HV) hh -= HV;
        int wc2 = ww * 7 + tw + 3; if (wc2 >= WV) wc2 -= WV;
        s_off[tid] = (((b * DV + d) * HV + hh) * WV + wc2) * CC;
    }

    const int wid = tid >> 6, lane = tid & 63;
    const int wr = wid >> 1, wc = wid & 1;
    const int lrow = lane & 15, kg = lane >> 4;

    f32x4 acc[4][4];
    f32x4 zero = {0.f, 0.f, 0.f, 0.f};
#pragma unroll
    for (int m = 0; m < 4; m++)
#pragma unroll
        for (int n = 0; n < 4; n++) acc[m][n] = zero;

    const int arow = tid >> 1, ahalf = tid & 1;

    for (int kc = 0; kc < KD / 32; kc++) {
        __syncthreads();
        if constexpr (ASRC_BF16) {
            const short* gp = (const short*)X + (size_t)(m0 + arow) * KD + kc * 32 + ahalf * 16;
            *(int4*)&Ah[arow][ahalf * 16]     = *(const int4*)(gp);
            *(int4*)&Ah[arow][ahalf * 16 + 8] = *(const int4*)(gp + 8);
        } else {
            const float* gp;
            if (QKV) gp = (const float*)X + s_off[arow] + kc * 32 + ahalf * 16;
            else     gp = (const float*)X + (size_t)(m0 + arow) * KD + kc * 32 + ahalf * 16;
            float4 a0 = *(const float4*)(gp);
            float4 a1 = *(const float4*)(gp + 4);
            float4 a2 = *(const float4*)(gp + 8);
            float4 a3 = *(const float4*)(gp + 12);
            if (QKV && z == 0 && blockIdx.y == 0) {
                float* rp = resid + (size_t)(m0 + arow) * CC + kc * 32 + ahalf * 16;
                *(float4*)(rp) = a0; *(float4*)(rp + 4) = a1;
                *(float4*)(rp + 8) = a2; *(float4*)(rp + 12) = a3;
            }
            float f[16] = {a0.x,a0.y,a0.z,a0.w, a1.x,a1.y,a1.z,a1.w,
                           a2.x,a2.y,a2.z,a2.w, a3.x,a3.y,a3.z,a3.w};
            int hi[8], lo[8];
#pragma unroll
            for (int e = 0; e < 8; e++) {
                unsigned short h0 = f2bf(f[2*e]),   h1 = f2bf(f[2*e+1]);
                float l0 = f[2*e] - bf2f(h0), l1 = f[2*e+1] - bf2f(h1);
                hi[e] = pack2(h0, h1);
                lo[e] = pack2(f2bf(l0), f2bf(l1));
            }
            int4* dh = (int4*)&Ah[arow][ahalf * 16];
            dh[0] = make_int4(hi[0], hi[1], hi[2], hi[3]);
            dh[1] = make_int4(hi[4], hi[5], hi[6], hi[7]);
            int4* dl = (int4*)&Al[arow][ahalf * 16];
            dl[0] = make_int4(lo[0], lo[1], lo[2], lo[3]);
            dl[1] = make_int4(lo[4], lo[5], lo[6], lo[7]);
        }
        {   // stage B (pre-split, straight copy)
            const short* sh = Wh + (size_t)(c0 + arow) * KD + kc * 32 + ahalf * 16;
            const short* sl = Wl + (size_t)(c0 + arow) * KD + kc * 32 + ahalf * 16;
            int4* dh = (int4*)&Bh[arow][ahalf * 16];
            dh[0] = *(const int4*)(sh); dh[1] = *(const int4*)(sh + 8);
            int4* dl = (int4*)&Bl[arow][ahalf * 16];
            dl[0] = *(const int4*)(sl); dl[1] = *(const int4*)(sl + 8);
        }
        __syncthreads();

        short8 afh[4], afl[4], bfh[4], bfl[4];
#pragma unroll
        for (int m = 0; m < 4; m++) {
            int r = wr * 64 + m * 16 + lrow;
            afh[m] = *(const short8*)&Ah[r][kg * 8];
            if constexpr (!ASRC_BF16) afl[m] = *(const short8*)&Al[r][kg * 8];
        }
#pragma unroll
        for (int n = 0; n < 4; n++) {
            int cidx = wc * 64 + n * 16 + lrow;
            bfh[n] = *(const short8*)&Bh[cidx][kg * 8];
            bfl[n] = *(const short8*)&Bl[cidx][kg * 8];
        }
#pragma unroll
        for (int m = 0; m < 4; m++)
#pragma unroll
            for (int n = 0; n < 4; n++) {
                acc[m][n] = __builtin_amdgcn_mfma_f32_16x16x32_bf16(afh[m], bfh[n], acc[m][n], 0, 0, 0);
                acc[m][n] = __builtin_amdgcn_mfma_f32_16x16x32_bf16(afh[m], bfl[n], acc[m][n], 0, 0, 0);
                if constexpr (!ASRC_BF16)
                    acc[m][n] = __builtin_amdgcn_mfma_f32_16x16x32_bf16(afl[m], bfh[n], acc[m][n], 0, 0, 0);
            }
    }

    // epilogue
#pragma unroll
    for (int n = 0; n < 4; n++) {
        int col = c0 + wc * 64 + n * 16 + lrow;
        float bv = bb[col];
#pragma unroll
        for (int m = 0; m < 4; m++) {
#pragma unroll
            for (int rg = 0; rg < 4; rg++) {
                int r = wr * 64 + m * 16 + kg * 4 + rg;
                float x = acc[m][n][rg] + bv;
                if (GELU) x = 0.5f * x * (1.f + erff(x * 0.70710678118654752f));
                int tok = m0 + r;
                if constexpr (QKV) {
                    int bw = (unsigned)tok / LL;
                    int l  = tok - bw * LL;
                    int head = col >> 5, hd = col & 31;
                    short* Yb = (short*)Y;
                    if (z == 2)
                        Yb[(((size_t)bw * NHH + head) * HDD + hd) * KPAD + l] = (short)f2bf(x);
                    else
                        Yb[(((size_t)bw * NHH + head) * LL + l) * HDD + hd] = (short)f2bf(x);
                } else if constexpr (AOUT_BF16) {
                    ((short*)Y)[(size_t)tok * ND + col] = (short)f2bf(x);
                } else {
                    ((float*)Y)[(size_t)tok * ND + col] = x;
                }
            }
        }
    }
}

// =====================================================================
// MFMA attention: block=(h,bn), 7 waves x 32 q-rows.
// K/V staged in LDS in MFMA-fragment order (conflict-free b128).
// Swapped QK^T: ST[k][q] = mfma(Kfrag, Qfrag).  Softmax in-register
// (no max-subtraction; pad/mask forced to exp->0 via -1e4/-100 bias).
// P routed through wave-private LDS frag buffer (same-wave DS in-order,
// no barriers), then O^T = mfma(Vt-frag, P-frag).
// =====================================================================
__global__ __launch_bounds__(448) void k_attn2(
    const short* __restrict__ Qb, const short* __restrict__ Kb, const short* __restrict__ Vt,
    const short* __restrict__ biasM, const short* __restrict__ maskM,
    float* __restrict__ ctx)
{
    __shared__ __align__(16) short Kf[14 * 64 * 8];   // 14 KB
    __shared__ __align__(16) short Vf[14 * 64 * 8];   // 14 KB
    __shared__ __align__(16) short Pf[7 * 7 * 64 * 8];// 50 KB (per-wave 3584)
    const int h = blockIdx.x, bn = blockIdx.y;
    const int w = bn & (NWW - 1);
    const int tid = threadIdx.x;
    const size_t kvb = (size_t)bn * NHH + h;

    // stage K fragments: A-layout row=lane&15 (ktok), k-elems=(lane>>4)*8 (hd)
    for (int f = tid; f < 14 * 64; f += 448) {
        int ln = f & 63, kt = f >> 6;
        int ktok = kt * 16 + (ln & 15);
        int hd0 = (ln >> 4) * 8;
        short8 val = {0,0,0,0,0,0,0,0};
        if (ktok < LL) val = *(const short8*)(Kb + (kvb * LL + ktok) * HDD + hd0);
        *(short8*)(Kf + f * 8) = val;
    }
    // stage V^T fragments: A-layout row=lane&15 (d), k-elems=(lane>>4)*8 (ktok)
    for (int f = tid; f < 14 * 64; f += 448) {
        int ln = f & 63, t2 = f >> 6;
        int dt = t2 & 1, kt32 = t2 >> 1;
        int d = dt * 16 + (ln & 15);
        int k0 = kt32 * 32 + (ln >> 4) * 8;
        *(short8*)(Vf + f * 8) = *(const short8*)(Vt + (kvb * HDD + d) * KPAD + k0);
    }
    __syncthreads();

    const int wv = tid >> 6, lane = tid & 63;
    const int qcol = lane & 15, kg = lane >> 4;
    const int qb = wv * 32;
    short* const myP = Pf + wv * 3584;
    const float scale = 0.17677669529663687f;

    for (int qt = 0; qt < 2; qt++) {
        const int q = qb + qt * 16 + qcol;
        const int qr = (q < LL) ? q : (LL - 1);
        short8 qf = *(const short8*)(Qb + (kvb * LL + qr) * HDD + kg * 8);

        f32x4 st[14];
#pragma unroll
        for (int kt = 0; kt < 14; kt++) {
            short8 kf = *(const short8*)(Kf + (kt * 64 + lane) * 8);
            f32x4 zz = {0.f, 0.f, 0.f, 0.f};
            st[kt] = __builtin_amdgcn_mfma_f32_16x16x32_bf16(kf, qf, zz, 0, 0, 0);
        }

        float psum = 0.f;
        const short* bp = biasM + ((size_t)h * QPAD + q) * KPAD;
        const short* mp = maskM + ((size_t)w * QPAD + q) * KPAD;
#pragma unroll
        for (int kt = 0; kt < 14; kt++) {
            int k0 = kt * 16 + kg * 4;
            short4 b4 = *(const short4*)(bp + k0);
            short4 m4 = *(const short4*)(mp + k0);
            float p0 = __expf(st[kt][0] * scale + bf2f((unsigned short)b4.x) + bf2f((unsigned short)m4.x));
            float p1 = __expf(st[kt][1] * scale + bf2f((unsigned short)b4.y) + bf2f((unsigned short)m4.y));
            float p2 = __expf(st[kt][2] * scale + bf2f((unsigned short)b4.z) + bf2f((unsigned short)m4.z));
            float p3 = __expf(st[kt][3] * scale + bf2f((unsigned short)b4.w) + bf2f((unsigned short)m4.w));
            st[kt][0] = p0; st[kt][1] = p1; st[kt][2] = p2; st[kt][3] = p3;
            psum += (p0 + p1) + (p2 + p3);
        }
        psum += __shfl_xor(psum, 16);
        psum += __shfl_xor(psum, 32);
        const float inv = 1.f / psum;

        // scatter P (bf16, pre-scaled) into wave-private frag buffer
#pragma unroll
        for (int kt = 0; kt < 14; kt++) {
            int I0 = pack2(f2bf(st[kt][0] * inv), f2bf(st[kt][1] * inv));
            int I1 = pack2(f2bf(st[kt][2] * inv), f2bf(st[kt][3] * inv));
            int kg_r = (kt & 1) * 2 + (kg >> 1);
            int slot = (kt >> 1) * 64 + kg_r * 16 + qcol;
            *(int2*)(myP + slot * 8 + (kg & 1) * 4) = make_int2(I0, I1);
        }

        f32x4 o0 = {0.f, 0.f, 0.f, 0.f}, o1 = {0.f, 0.f, 0.f, 0.f};
#pragma unroll
        for (int kt32 = 0; kt32 < 7; kt32++) {
            short8 pf = *(const short8*)(myP + (kt32 * 64 + lane) * 8);
            short8 v0 = *(const short8*)(Vf + ((kt32 * 2 + 0) * 64 + lane) * 8);
            short8 v1 = *(const short8*)(Vf + ((kt32 * 2 + 1) * 64 + lane) * 8);
            o0 = __builtin_amdgcn_mfma_f32_16x16x32_bf16(v0, pf, o0, 0, 0, 0);
            o1 = __builtin_amdgcn_mfma_f32_16x16x32_bf16(v1, pf, o1, 0, 0, 0);
        }
        if (q < LL) {
            float* cp = ctx + ((size_t)bn * LL + q) * PP + h * HDD;
#pragma unroll
            for (int rg = 0; rg < 4; rg++) {
                cp[kg * 4 + rg]      = o0[rg];
                cp[16 + kg * 4 + rg] = o1[rg];
            }
        }
    }
}

// =====================================================================
// LN (+residual add).  One wave per row of 128.
// =====================================================================
__global__ __launch_bounds__(256) void k_ln_add(
    const float* __restrict__ X, const float* __restrict__ gg, const float* __restrict__ bb,
    const float* __restrict__ res, float* __restrict__ Y)
{
    const int row = blockIdx.x * 4 + (threadIdx.x >> 6);
    const int lane = threadIdx.x & 63;
    const float2 v = ((const float2*)(X + (size_t)row * CC))[lane];
    float s = v.x + v.y, s2 = v.x * v.x + v.y * v.y;
#pragma unroll
    for (int m = 1; m < 64; m <<= 1) { s += __shfl_xor(s, m); s2 += __shfl_xor(s2, m); }
    const float mean = s * 0.0078125f;
    const float var  = s2 * 0.0078125f - mean * mean;
    const float rinv = rsqrtf(var + 1e-5f);
    const float2 g2 = ((const float2*)gg)[lane];
    const float2 b2 = ((const float2*)bb)[lane];
    const float2 r2 = ((const float2*)(res + (size_t)row * CC))[lane];
    float2 o;
    o.x = (v.x - mean) * rinv * g2.x + b2.x + r2.x;
    o.y = (v.y - mean) * rinv * g2.y + b2.y + r2.y;
    ((float2*)(Y + (size_t)row * CC))[lane] = o;
}

// =====================================================================
// LN2 + residual + reverse-partition + roll(+2,+3,+3) scatter to output
// =====================================================================
__global__ __launch_bounds__(256) void k_ln2_scatter(
    const float* __restrict__ X, const float* __restrict__ gg, const float* __restrict__ bb,
    const float* __restrict__ res, float* __restrict__ out)
{
    const int row = blockIdx.x * 4 + (threadIdx.x >> 6);
    const int lane = threadIdx.x & 63;
    const float2 v = ((const float2*)(X + (size_t)row * CC))[lane];
    float s = v.x + v.y, s2 = v.x * v.x + v.y * v.y;
#pragma unroll
    for (int m = 1; m < 64; m <<= 1) { s += __shfl_xor(s, m); s2 += __shfl_xor(s2, m); }
    const float mean = s * 0.0078125f;
    const float var  = s2 * 0.0078125f - mean * mean;
    const float rinv = rsqrtf(var + 1e-5f);
    const float2 g2 = ((const float2*)gg)[lane];
    const float2 b2 = ((const float2*)bb)[lane];
    const float2 r2 = ((const float2*)(res + (size_t)row * CC))[lane];
    float2 o;
    o.x = (v.x - mean) * rinv * g2.x + b2.x + r2.x;
    o.y = (v.y - mean) * rinv * g2.y + b2.y + r2.y;

    int l = row % LL, bw = row / LL;
    int w = bw & (NWW - 1), b = bw >> 7;
    int wd = w >> 6, wh = (w >> 3) & 7, ww = w & 7;
    int td = l / 49, r = l % 49, th = r / 7, tw = r % 7;
    int d  = wd * 4 + td + 2;  if (d  >= DV) d  -= DV;
    int hh = wh * 7 + th + 3;  if (hh >= HV) hh -= HV;
    int wc = ww * 7 + tw + 3;  if (wc >= WV) wc -= WV;
    size_t dest = (((size_t)(b * DV + d) * HV + hh) * WV + wc) * CC;
    ((float2*)(out + dest))[lane] = o;
}

// =====================================================================
extern "C" void kernel_launch(void* const* d_in, const int* in_sizes, int n_in,
                              void* d_out, int out_size, void* d_ws, size_t ws_size,
                              hipStream_t stream)
{
    (void)in_sizes; (void)n_in; (void)out_size;
    const float* q    = (const float*)d_in[0];
    const float* k    = (const float*)d_in[1];
    const float* v    = (const float*)d_in[2];
    const float* bq   = (const float*)d_in[4];
    const float* bk   = (const float*)d_in[6];
    const float* bv   = (const float*)d_in[8];
    const float* bo   = (const float*)d_in[10];
    const float* rtab = (const float*)d_in[11];
    const float* g1   = (const float*)d_in[12];
    const float* b1n  = (const float*)d_in[13];
    const float* b1m  = (const float*)d_in[15];
    const float* b2m  = (const float*)d_in[17];
    const float* g2   = (const float*)d_in[18];
    const float* b2n  = (const float*)d_in[19];
    const int*   ridx = (const int*)d_in[20];
    const float* msk  = (const float*)d_in[21];
    float* out = (float*)d_out;
    char*  base = (char*)d_ws;

    // byte offsets (all 16B aligned)
    float* resid = (float*)(base);                          // 25,690,112
    short* Qb    = (short*)(base + 25690112);               // 25,690,112
    short* Kb2   = (short*)(base + 51380224);               // 25,690,112
    short* Vt    = (short*)(base + 77070336);               // 29,360,128
    float* ctxb  = (float*)(base + 106430464);              // 51,380,224
    short* biasM = (short*)(base + 157810688);              //    802,816
    short* maskM = (short*)(base + 158613504);              // 12,845,056
    float* h2    = (float*)(base + 171458560);              // 25,690,112
    // overlays
    float* proj1 = (float*)(base + 25690112);               // Qb region (dead after attn)
    float* attnb = (float*)(base + 51380224);               // Kb region (dead after attn)
    short* h1    = (short*)(base + 77070336);               // Vt+ctx region (38.5MB <= 80.7MB)

    short* WT = (short*)d_out;   // weight scratch; d_out fully overwritten at end

    const size_t need = 197148672;
    if (ws_size < need) return;

    k_wprep<<<dim3(WT_TOTAL / 256), dim3(256), 0, stream>>>(
        (const float*)d_in[3], (const float*)d_in[5], (const float*)d_in[7],
        (const float*)d_in[9], (const float*)d_in[14], (const float*)d_in[16], WT);
    k_tab<<<dim3(NHH * QPAD * KPAD / 256), dim3(256), 0, stream>>>(rtab, ridx, biasM);
    k_maskpad<<<dim3(NWW * QPAD * KPAD / 256), dim3(256), 0, stream>>>(msk, maskM);

    k_mgemm<128, 256, 0, 1, 0, 0><<<dim3(TT / 128, 2, 3), dim3(256), 0, stream>>>(
        q, k, v, WT + WT_OQ, WT + WT_TOTAL + WT_OQ,
        bq, bk, bv, Qb, Kb2, Vt, resid);

    k_attn2<<<dim3(NHH, BNN), dim3(448), 0, stream>>>(Qb, Kb2, Vt, biasM, maskM, ctxb);

    k_mgemm<256, 128, 0, 0, 0, 0><<<dim3(TT / 128, 1), dim3(256), 0, stream>>>(
        ctxb, ctxb, ctxb, WT + WT_OO, WT + WT_TOTAL + WT_OO,
        bo, bo, bo, proj1, proj1, proj1, nullptr);

    k_ln_add<<<dim3(TT / 4), dim3(256), 0, stream>>>(proj1, g1, b1n, resid, attnb);

    k_mgemm<128, 384, 1, 0, 0, 1><<<dim3(TT / 128, 3), dim3(256), 0, stream>>>(
        attnb, attnb, attnb, WT + WT_O1, WT + WT_TOTAL + WT_O1,
        b1m, b1m, b1m, h1, h1, h1, nullptr);

    k_mgemm<384, 128, 0, 0, 1, 0><<<dim3(TT / 128, 1), dim3(256), 0, stream>>>(
        h1, h1, h1, WT + WT_O2, WT + WT_TOTAL + WT_O2,
        b2m, b2m, b2m, h2, h2, h2, nullptr);

    k_ln2_scatter<<<dim3(TT / 4), dim3(256), 0, stream>>>(h2, g2, b2n, attnb, out);
}

// Round 6
// 442.377 us; speedup vs baseline: 2.5271x; 1.0183x over previous
//
#include <hip/hip_runtime.h>
#include <math.h>

// ---- problem constants ----
#define CC   128
#define PP   256
#define NHH  8
#define HDD  32
#define HIDD 384
#define LL   196
#define NWW  128
#define BNN  256          // B*NW
#define TT   50176        // BNN*LL
#define DV   8
#define HV   56
#define WV   56
#define KPAD 224
#define QPAD 224
#define TB16 3136         // TT/16

typedef __attribute__((ext_vector_type(8))) short short8;
typedef __attribute__((ext_vector_type(4))) float f32x4;

// weight panel regions (shorts per plane)
#define WT_OQ 0
#define WT_OO 98304
#define WT_O1 131072
#define WT_O2 180224
#define WT_TOTAL 229376

// workspace byte offsets
#define O_RESID  0u
#define O_GP     25690112u
#define O_QF     102760448u
#define O_KF     132120576u
#define O_VF     161480704u
#define O_BIAS   190840832u
#define O_MASK   192446464u
#define O_CTXP   25690112u
#define O_PROJ1  51380224u
#define O_ATTNB  102760448u
#define O_ATTP   132120576u
#define O_H1P    161480704u
#define O_H2     77070336u
#define GP_PL    6422528    // shorts per A-plane [T][128]
#define ATT_PL   6422528
#define WS_NEED  205291520u

__device__ __forceinline__ unsigned short f2bf(float x){
    unsigned u = __float_as_uint(x);
    u += 0x7FFFu + ((u >> 16) & 1u);
    return (unsigned short)(u >> 16);
}
__device__ __forceinline__ float bf2f(unsigned short h){
    return __uint_as_float(((unsigned)h) << 16);
}
__device__ __forceinline__ int pack2(unsigned short a, unsigned short b){
    return (int)(unsigned)a | ((int)(unsigned)b << 16);
}
__device__ __forceinline__ void gload16(const void* g, void* l){
    __builtin_amdgcn_global_load_lds(
        (const __attribute__((address_space(1))) void*)g,
        (__attribute__((address_space(3))) void*)l, 16, 0, 0);
}
__device__ __forceinline__ int roll_off(int tok){
    int l = tok % LL, bw = tok / LL;
    int w = bw & (NWW - 1), b = bw >> 7;
    int wd = w >> 6, wh = (w >> 3) & 7, ww = w & 7;
    int td = l / 49, r = l % 49, th = r / 7, tw = r % 7;
    int d  = wd * 4 + td + 2;  if (d  >= DV) d  -= DV;
    int hh = wh * 7 + th + 3;  if (hh >= HV) hh -= HV;
    int wc = ww * 7 + tw + 3;  if (wc >= WV) wc -= WV;
    return (((b * DV + d) * HV + hh) * WV + wc) * CC;
}

// =====================================================================
// weight prep: fp32 W -> split bf16 B-panels [kc][nblk][64lane][8]
// lane = (n&15) + ((k&31)>>3)*16, elems = k&7
// =====================================================================
__global__ __launch_bounds__(256) void k_wprep2(
    const float* __restrict__ Wq, const float* __restrict__ Wk, const float* __restrict__ Wv,
    const float* __restrict__ Wo, const float* __restrict__ W1, const float* __restrict__ W2,
    short* __restrict__ WT)
{
    int t = blockIdx.x * 256 + threadIdx.x;
    if (t >= WT_TOTAL) return;
    const float* src; int ndf, rel;
    if (t < WT_OO)      { src = (t >> 15) == 0 ? Wq : ((t >> 15) == 1 ? Wk : Wv); ndf = 256; rel = t & 32767; }
    else if (t < WT_O1) { src = Wo; ndf = 128; rel = t - WT_OO; }
    else if (t < WT_O2) { src = W1; ndf = 384; rel = t - WT_O1; }
    else                { src = W2; ndf = 128; rel = t - WT_O2; }
    int per_kc = (ndf / 16) * 512;
    int kc = rel / per_kc, r2 = rel % per_kc;
    int nblk = r2 >> 9, ln = (r2 >> 3) & 63, e = r2 & 7;
    int n = nblk * 16 + (ln & 15);
    int k = kc * 32 + (ln >> 4) * 8 + e;
    float v = src[(size_t)k * ndf + n];
    unsigned short h = f2bf(v);
    WT[t] = (short)h;
    WT[WT_TOTAL + t] = (short)f2bf(v - bf2f(h));
}

// =====================================================================
// gather: roll+partition + bf16 split -> A-panels for q,k,v + resid fp32
// =====================================================================
__global__ __launch_bounds__(256) void k_gather(
    const float* __restrict__ qs, const float* __restrict__ ks, const float* __restrict__ vs,
    short* __restrict__ Gp, float* __restrict__ resid)
{
    const int tid = threadIdx.x;
    const int tok = blockIdx.x * 16 + (tid >> 4);
    const int j = tid & 15;                    // c = j*8 .. j*8+7
    const int off = roll_off(tok) + j * 8;
    const int kc = j >> 2, k8 = j & 3;
    const size_t slot = (((size_t)kc * TB16 + (tok >> 4)) * 64 + (tok & 15) + k8 * 16) * 8;
    const float* srcs[3] = {qs, ks, vs};
#pragma unroll
    for (int z = 0; z < 3; z++) {
        float4 a0 = *(const float4*)(srcs[z] + off);
        float4 a1 = *(const float4*)(srcs[z] + off + 4);
        float f[8] = {a0.x,a0.y,a0.z,a0.w,a1.x,a1.y,a1.z,a1.w};
        short8 hi, lo;
#pragma unroll
        for (int e = 0; e < 8; e++) {
            unsigned short h = f2bf(f[e]);
            hi[e] = (short)h;
            lo[e] = (short)f2bf(f[e] - bf2f(h));
        }
        *(short8*)(Gp + (size_t)(z * 2 + 0) * GP_PL + slot) = hi;
        *(short8*)(Gp + (size_t)(z * 2 + 1) * GP_PL + slot) = lo;
        if (z == 0) {
            float* rp = resid + (size_t)tok * CC + j * 8;
            *(float4*)rp = a0; *(float4*)(rp + 4) = a1;
        }
    }
}

// =====================================================================
// bias table with window-parity k-slot shift: biasM2[h][par][q][kslot]
// kslot maps to key token l = kslot - 4*par; out of range -> -1e4
// =====================================================================
__global__ __launch_bounds__(256) void k_tab2(const float* __restrict__ tbl,
                                              const int* __restrict__ idx,
                                              short* __restrict__ biasM)
{
    int t = blockIdx.x * 256 + threadIdx.x;
    if (t >= NHH * 2 * QPAD * KPAD) return;
    int ks = t % KPAD, q = (t / KPAD) % QPAD;
    int par = (t / (KPAD * QPAD)) & 1, h = t / (KPAD * QPAD * 2);
    int l = ks - 4 * par;
    float v = (q < LL && l >= 0 && l < LL) ? tbl[idx[q * LL + l] * NHH + h] : -1.0e4f;
    biasM[t] = (short)f2bf(v);
}

__global__ __launch_bounds__(256) void k_maskpad2(const float* __restrict__ msk,
                                                  short* __restrict__ maskM)
{
    int t = blockIdx.x * 256 + threadIdx.x;
    if (t >= NWW * QPAD * KPAD) return;
    int ks = t % KPAD, q = (t / KPAD) % QPAD, w = t / (KPAD * QPAD);
    int l = ks - 4 * (w & 1);
    float v = (q < LL && l >= 0 && l < LL) ? msk[((size_t)w * LL + q) * LL + l] : 0.f;
    maskM[t] = (short)f2bf(v);
}

// =====================================================================
// panelized MFMA GEMM.  8 waves of 64x64.  A/B panels staged with
// global_load_lds (frag-linear LDS => conflict-free ds_read_b128).
// EPI 0: fp32 [T][NDF].  EPI 1: QKV -> attn frag arrays (z==0: Q frags
// unshifted; z==1: K frags at parity-shifted k-slots; z==2: V^T frags,
// parity-shifted).  EPI 2: gelu -> bf16 A-panel (H1p).
// =====================================================================
template<int MT, int NT, int KD, int APL, int NDF, int EPI>
__global__ __launch_bounds__(512) void mgemm2(
    const short* __restrict__ A0, const short* __restrict__ A1,
    const short* __restrict__ WhB, const short* __restrict__ WlB,
    const float* __restrict__ b0, const float* __restrict__ b1, const float* __restrict__ b2,
    void* __restrict__ Y0, void* __restrict__ Y1, void* __restrict__ Y2)
{
    constexpr int ACH = APL * MT / 16;
    constexpr int NCH = ACH + 2 * (NT / 16);
    __shared__ __align__(16) short smem[NCH * 512];

    const int tid = threadIdx.x;
    const int wid = tid >> 6, lane = tid & 63;
    constexpr int WN = NT / 64;
    const int wm = wid / WN, wn = wid % WN;
    const int lrow = lane & 15, kg = lane >> 4;
    const int m0 = blockIdx.x * MT;
    const int c0 = blockIdx.y * NT;
    const int z = (EPI == 1) ? blockIdx.z : 0;

    const short* Ap0 = (EPI == 1) ? A0 + (size_t)(z * 2) * GP_PL : A0;
    const short* Ap1 = (EPI == 1) ? A0 + (size_t)(z * 2 + 1) * GP_PL : A1;
    const short* Wh = WhB + (EPI == 1 ? z * 32768 : 0);
    const short* Wl = WlB + (EPI == 1 ? z * 32768 : 0);
    const float* bb = (z == 0) ? b0 : (z == 1) ? b1 : b2;

    f32x4 acc[4][4];
    f32x4 zero = {0.f,0.f,0.f,0.f};
#pragma unroll
    for (int i = 0; i < 4; i++)
#pragma unroll
        for (int j = 0; j < 4; j++) acc[i][j] = zero;

    for (int kc = 0; kc < KD / 32; kc++) {
        __syncthreads();
        for (int c = wid; c < NCH; c += 8) {
            const short* src;
            if (c < ACH) {
                int pl = c / (MT / 16), fb = c % (MT / 16);
                src = (pl ? Ap1 : Ap0) + ((size_t)kc * TB16 + m0 / 16 + fb) * 512;
            } else {
                int c2 = c - ACH;
                int pl = c2 / (NT / 16), fb = c2 % (NT / 16);
                src = (pl ? Wl : Wh) + ((size_t)kc * (NDF / 16) + c0 / 16 + fb) * 512;
            }
            gload16(src + lane * 8, &smem[c * 512]);
        }
        __syncthreads();

        short8 bh[4], bl[4];
#pragma unroll
        for (int j = 0; j < 4; j++) {
            bh[j] = *(const short8*)&smem[(ACH + wn * 4 + j) * 512 + lane * 8];
            bl[j] = *(const short8*)&smem[(ACH + NT / 16 + wn * 4 + j) * 512 + lane * 8];
        }
#pragma unroll
        for (int i = 0; i < 4; i++) {
            short8 ah = *(const short8*)&smem[(wm * 4 + i) * 512 + lane * 8];
            short8 al;
            if constexpr (APL == 2) al = *(const short8*)&smem[(MT / 16 + wm * 4 + i) * 512 + lane * 8];
#pragma unroll
            for (int j = 0; j < 4; j++) {
                acc[i][j] = __builtin_amdgcn_mfma_f32_16x16x32_bf16(ah, bh[j], acc[i][j], 0, 0, 0);
                acc[i][j] = __builtin_amdgcn_mfma_f32_16x16x32_bf16(ah, bl[j], acc[i][j], 0, 0, 0);
                if constexpr (APL == 2)
                    acc[i][j] = __builtin_amdgcn_mfma_f32_16x16x32_bf16(al, bh[j], acc[i][j], 0, 0, 0);
            }
        }
    }
    __syncthreads();   // staging LDS now reusable as bounce

    float bv[4];
#pragma unroll
    for (int j = 0; j < 4; j++) bv[j] = bb[c0 + wn * 64 + j * 16 + lrow];

    if constexpr (EPI == 0) {
        float* Y = (float*)Y0;
#pragma unroll
        for (int j = 0; j < 4; j++) {
            int col = c0 + wn * 64 + j * 16 + lrow;
#pragma unroll
            for (int i = 0; i < 4; i++)
#pragma unroll
                for (int rg = 0; rg < 4; rg++) {
                    int tok = m0 + wm * 64 + i * 16 + kg * 4 + rg;
                    Y[(size_t)tok * NDF + col] = acc[i][j][rg] + bv[j];
                }
        }
        return;
    }

    short* bw = smem + wid * 2048;

    if constexpr (EPI == 1) if (z == 2) {
        // ---- V path: col-major bounce [32 d][64 tok], parity k-slots ----
        short* VF = (short*)Y2;
#pragma unroll
        for (int hp = 0; hp < 2; hp++) {
#pragma unroll
            for (int jj = 0; jj < 2; jj++) {
                int j = hp * 2 + jj;
                int colL = jj * 16 + lrow;
#pragma unroll
                for (int i = 0; i < 4; i++) {
                    int tokL0 = i * 16 + kg * 4;
                    short4 pk;
                    pk.x = (short)f2bf(acc[i][j][0] + bv[j]);
                    pk.y = (short)f2bf(acc[i][j][1] + bv[j]);
                    pk.z = (short)f2bf(acc[i][j][2] + bv[j]);
                    pk.w = (short)f2bf(acc[i][j][3] + bv[j]);
                    *(short4*)&bw[colL * 64 + (tokL0 ^ ((colL & 7) << 3))] = pk;
                }
            }
            int head = (wn * 64 + hp * 32) >> 5;
#pragma unroll
            for (int it = 0; it < 4; it++) {
                int d = lrow + (it & 1) * 16;
                int ti0 = (kg + (it >> 1) * 4) * 8;
                short8 v = *(const short8*)&bw[d * 64 + (ti0 ^ ((d & 7) << 3))];
                int tok0 = m0 + wm * 64 + ti0;
                int bnA = tok0 / LL, bnB = (tok0 + 7) / LL;
                if (bnA == bnB) {
                    int ks0 = tok0 - bnA * LL + 4 * (bnA & 1);
                    size_t o = ((((size_t)bnA * NHH + head) * 14 + (ks0 >> 5) * 2 + (d >> 4)) * 64
                                + (d & 15) + ((ks0 >> 3) & 3) * 16) * 8;
                    *(short8*)(VF + o) = v;
                } else {
#pragma unroll
                    for (int e = 0; e < 8; e++) {
                        int tok = tok0 + e;
                        int bn = tok / LL;
                        int ks = tok - bn * LL + 4 * (bn & 1);
                        size_t o = ((((size_t)bn * NHH + head) * 14 + (ks >> 5) * 2 + (d >> 4)) * 64
                                    + (d & 15) + ((ks >> 3) & 3) * 16) * 8 + (ks & 7);
                        VF[o] = v[e];
                    }
                }
            }
            __builtin_amdgcn_sched_barrier(0);
        }
        return;
    }

    // ---- Q/K frag path (EPI==1 z<2) and panel path (EPI==2) ----
    if constexpr (EPI == 1 || EPI == 2) {
        short* F = (EPI == 2) ? (short*)Y0 : (short*)(z == 0 ? Y0 : Y1);
#pragma unroll
        for (int hp = 0; hp < 2; hp++) {
#pragma unroll
            for (int jj = 0; jj < 2; jj++) {
                int j = hp * 2 + jj;
#pragma unroll
                for (int i = 0; i < 4; i++)
#pragma unroll
                    for (int rg = 0; rg < 4; rg++) {
                        int tokL = i * 16 + kg * 4 + rg;
                        int colL = jj * 16 + lrow;
                        float x = acc[i][j][rg] + bv[j];
                        if constexpr (EPI == 2)
                            x = 0.5f * x * (1.f + erff(x * 0.70710678118654752f));
                        bw[tokL * 32 + (colL ^ (kg << 3))] = (short)f2bf(x);
                    }
            }
#pragma unroll
            for (int it = 0; it < 4; it++) {
                int tokL = it * 16 + lrow;
                int swr = (tokL >> 2) & 3;
                short8 v = *(const short8*)&bw[tokL * 32 + ((kg * 8) ^ (swr << 3))];
                int tok = m0 + wm * 64 + tokL;
                if constexpr (EPI == 1) {
                    int head = (wn * 64 + hp * 32) >> 5;
                    int bn = tok / LL, l = tok - bn * LL;
                    int slot = (z == 1) ? l + 4 * (bn & 1) : l;   // K parity shift
                    size_t o = ((((size_t)bn * NHH + head) * 14 + (slot >> 4)) * 64
                                + (slot & 15) + kg * 16) * 8;
                    *(short8*)(F + o) = v;
                } else {
                    int kglob = c0 + wn * 64 + hp * 32 + kg * 8;
                    size_t o = (((size_t)(kglob >> 5) * TB16 + (tok >> 4)) * 64
                                + (tok & 15) + ((kglob & 31) >> 3) * 16) * 8;
                    *(short8*)(F + o) = v;
                }
            }
            __builtin_amdgcn_sched_barrier(0);
        }
    }
}

// =====================================================================
// MFMA attention, frag inputs.  7 waves x 32 q.  Swapped QK^T, P via
// wave-private LDS, PV from V^T frags, epilogue -> bf16 ctx A-panels.
// =====================================================================
__global__ __launch_bounds__(448) void k_attn2(
    const short* __restrict__ QF, const short* __restrict__ KF, const short* __restrict__ VF,
    const short* __restrict__ biasM, const short* __restrict__ maskM,
    short* __restrict__ CTXp)
{
    __shared__ __align__(16) short Kf[14 * 64 * 8];
    __shared__ __align__(16) short Vf[14 * 64 * 8];
    __shared__ __align__(16) short Pf[7 * 7 * 64 * 8];
    const int h = blockIdx.x, bn = blockIdx.y;
    const int w = bn & (NWW - 1);
    const int par = bn & 1;
    const int tid = threadIdx.x;
    const size_t kvb = (size_t)bn * NHH + h;

    for (int f = tid; f < 14 * 64; f += 448) {
        *(short8*)(Kf + f * 8) = *(const short8*)(KF + (kvb * 14 * 64 + f) * 8);
        *(short8*)(Vf + f * 8) = *(const short8*)(VF + (kvb * 14 * 64 + f) * 8);
    }
    __syncthreads();

    const int wv = tid >> 6, lane = tid & 63;
    const int qcol = lane & 15, kg = lane >> 4;
    const int qb = wv * 32;
    short* const myP = Pf + wv * 3584;
    const float scale = 0.17677669529663687f;

    for (int qt = 0; qt < 2; qt++) {
        const int q = qb + qt * 16 + qcol;
        short8 qf = *(const short8*)(QF + ((kvb * 14 + (q >> 4)) * 64 + (q & 15) + kg * 16) * 8);

        f32x4 st[14];
#pragma unroll
        for (int kt = 0; kt < 14; kt++) {
            short8 kf = *(const short8*)(Kf + (kt * 64 + lane) * 8);
            f32x4 zz = {0.f,0.f,0.f,0.f};
            st[kt] = __builtin_amdgcn_mfma_f32_16x16x32_bf16(kf, qf, zz, 0, 0, 0);
        }

        float psum = 0.f;
        const short* bp = biasM + (((size_t)h * 2 + par) * QPAD + q) * KPAD;
        const short* mp = maskM + ((size_t)w * QPAD + q) * KPAD;
#pragma unroll
        for (int kt = 0; kt < 14; kt++) {
            int k0 = kt * 16 + kg * 4;
            short4 b4 = *(const short4*)(bp + k0);
            short4 m4 = *(const short4*)(mp + k0);
            float p0 = __expf(st[kt][0] * scale + bf2f((unsigned short)b4.x) + bf2f((unsigned short)m4.x));
            float p1 = __expf(st[kt][1] * scale + bf2f((unsigned short)b4.y) + bf2f((unsigned short)m4.y));
            float p2 = __expf(st[kt][2] * scale + bf2f((unsigned short)b4.z) + bf2f((unsigned short)m4.z));
            float p3 = __expf(st[kt][3] * scale + bf2f((unsigned short)b4.w) + bf2f((unsigned short)m4.w));
            st[kt][0] = p0; st[kt][1] = p1; st[kt][2] = p2; st[kt][3] = p3;
            psum += (p0 + p1) + (p2 + p3);
        }
        psum += __shfl_xor(psum, 16);
        psum += __shfl_xor(psum, 32);
        const float inv = 1.f / psum;

#pragma unroll
        for (int kt = 0; kt < 14; kt++) {
            int I0 = pack2(f2bf(st[kt][0] * inv), f2bf(st[kt][1] * inv));
            int I1 = pack2(f2bf(st[kt][2] * inv), f2bf(st[kt][3] * inv));
            int kg_r = (kt & 1) * 2 + (kg >> 1);
            int slot = (kt >> 1) * 64 + kg_r * 16 + qcol;
            *(int2*)(myP + slot * 8 + (kg & 1) * 4) = make_int2(I0, I1);
        }

        f32x4 o0 = {0.f,0.f,0.f,0.f}, o1 = {0.f,0.f,0.f,0.f};
#pragma unroll
        for (int kt32 = 0; kt32 < 7; kt32++) {
            short8 pf = *(const short8*)(myP + (kt32 * 64 + lane) * 8);
            short8 v0 = *(const short8*)(Vf + ((kt32 * 2 + 0) * 64 + lane) * 8);
            short8 v1 = *(const short8*)(Vf + ((kt32 * 2 + 1) * 64 + lane) * 8);
            o0 = __builtin_amdgcn_mfma_f32_16x16x32_bf16(v0, pf, o0, 0, 0, 0);
            o1 = __builtin_amdgcn_mfma_f32_16x16x32_bf16(v1, pf, o1, 0, 0, 0);
        }
        __builtin_amdgcn_sched_barrier(0);

        // bounce (bf16, short-typed; reuses myP region) -> ctx A-panel
        {
            int sw = (qcol & 7) << 2;
            short4 s0, s1;
            s0.x = (short)f2bf(o0[0]); s0.y = (short)f2bf(o0[1]);
            s0.z = (short)f2bf(o0[2]); s0.w = (short)f2bf(o0[3]);
            s1.x = (short)f2bf(o1[0]); s1.y = (short)f2bf(o1[1]);
            s1.z = (short)f2bf(o1[2]); s1.w = (short)f2bf(o1[3]);
            *(short4*)&myP[qcol * 32 + ((kg * 4) ^ sw)] = s0;
            *(short4*)&myP[qcol * 32 + ((16 + kg * 4) ^ sw)] = s1;
        }
        {
            int qr = qb + qt * 16 + (lane & 15);
            int k8 = lane >> 4;
            int sw = ((lane & 15) & 7) << 2;
            short4 a = *(const short4*)&myP[(lane & 15) * 32 + ((k8 * 8) ^ sw)];
            short4 b = *(const short4*)&myP[(lane & 15) * 32 + ((k8 * 8 + 4) ^ sw)];
            if (qr < LL) {
                int tok = bn * LL + qr;
                short8 o = {a.x, a.y, a.z, a.w, b.x, b.y, b.z, b.w};
                size_t dst = (((size_t)h * TB16 + (tok >> 4)) * 64 + (tok & 15) + k8 * 16) * 8;
                *(short8*)(CTXp + dst) = o;
            }
        }
        __builtin_amdgcn_sched_barrier(0);
    }
}

// =====================================================================
// LN1 + residual: 16 threads/row.  Outputs fp32 rows (attnb) + split
// bf16 A-panels (ATTp) for MLP1.
// =====================================================================
__global__ __launch_bounds__(256) void k_ln_panel(
    const float* __restrict__ X, const float* __restrict__ gg, const float* __restrict__ bbv,
    const float* __restrict__ res, float* __restrict__ Y, short* __restrict__ ATTp)
{
    const int row = blockIdx.x * 16 + (threadIdx.x >> 4);
    const int j = threadIdx.x & 15;
    const float4 x0 = *(const float4*)(X + (size_t)row * CC + j * 8);
    const float4 x1 = *(const float4*)(X + (size_t)row * CC + j * 8 + 4);
    float s  = x0.x+x0.y+x0.z+x0.w + x1.x+x1.y+x1.z+x1.w;
    float s2 = x0.x*x0.x+x0.y*x0.y+x0.z*x0.z+x0.w*x0.w
             + x1.x*x1.x+x1.y*x1.y+x1.z*x1.z+x1.w*x1.w;
#pragma unroll
    for (int m = 1; m < 16; m <<= 1) { s += __shfl_xor(s, m); s2 += __shfl_xor(s2, m); }
    const float mean = s * 0.0078125f;
    const float var  = s2 * 0.0078125f - mean * mean;
    const float rinv = rsqrtf(var + 1e-5f);
    const float4 g0 = *(const float4*)(gg + j * 8);
    const float4 g1 = *(const float4*)(gg + j * 8 + 4);
    const float4 b0 = *(const float4*)(bbv + j * 8);
    const float4 b1 = *(const float4*)(bbv + j * 8 + 4);
    const float4 r0 = *(const float4*)(res + (size_t)row * CC + j * 8);
    const float4 r1 = *(const float4*)(res + (size_t)row * CC + j * 8 + 4);
    float o[8];
    o[0] = (x0.x-mean)*rinv*g0.x + b0.x + r0.x;
    o[1] = (x0.y-mean)*rinv*g0.y + b0.y + r0.y;
    o[2] = (x0.z-mean)*rinv*g0.z + b0.z + r0.z;
    o[3] = (x0.w-mean)*rinv*g0.w + b0.w + r0.w;
    o[4] = (x1.x-mean)*rinv*g1.x + b1.x + r1.x;
    o[5] = (x1.y-mean)*rinv*g1.y + b1.y + r1.y;
    o[6] = (x1.z-mean)*rinv*g1.z + b1.z + r1.z;
    o[7] = (x1.w-mean)*rinv*g1.w + b1.w + r1.w;
    float* yp = Y + (size_t)row * CC + j * 8;
    *(float4*)yp = make_float4(o[0],o[1],o[2],o[3]);
    *(float4*)(yp+4) = make_float4(o[4],o[5],o[6],o[7]);
    short8 hi, lo;
#pragma unroll
    for (int e = 0; e < 8; e++) {
        unsigned short hh = f2bf(o[e]);
        hi[e] = (short)hh;
        lo[e] = (short)f2bf(o[e] - bf2f(hh));
    }
    size_t slot = (((size_t)(j >> 2) * TB16 + (row >> 4)) * 64 + (row & 15) + (j & 3) * 16) * 8;
    *(short8*)(ATTp + slot) = hi;
    *(short8*)(ATTp + ATT_PL + slot) = lo;
}

// =====================================================================
// LN2 + residual + reverse + roll scatter
// =====================================================================
__global__ __launch_bounds__(256) void k_ln2_scatter(
    const float* __restrict__ X, const float* __restrict__ gg, const float* __restrict__ bb,
    const float* __restrict__ res, float* __restrict__ out)
{
    const int row = blockIdx.x * 4 + (threadIdx.x >> 6);
    const int lane = threadIdx.x & 63;
    const float2 v = ((const float2*)(X + (size_t)row * CC))[lane];
    float s = v.x + v.y, s2 = v.x * v.x + v.y * v.y;
#pragma unroll
    for (int m = 1; m < 64; m <<= 1) { s += __shfl_xor(s, m); s2 += __shfl_xor(s2, m); }
    const float mean = s * 0.0078125f;
    const float var  = s2 * 0.0078125f - mean * mean;
    const float rinv = rsqrtf(var + 1e-5f);
    const float2 g2 = ((const float2*)gg)[lane];
    const float2 b2 = ((const float2*)bb)[lane];
    const float2 r2 = ((const float2*)(res + (size_t)row * CC))[lane];
    float2 o;
    o.x = (v.x - mean) * rinv * g2.x + b2.x + r2.x;
    o.y = (v.y - mean) * rinv * g2.y + b2.y + r2.y;
    ((float2*)(out + roll_off(row)))[lane] = o;
}

// =====================================================================
extern "C" void kernel_launch(void* const* d_in, const int* in_sizes, int n_in,
                              void* d_out, int out_size, void* d_ws, size_t ws_size,
                              hipStream_t stream)
{
    (void)in_sizes; (void)n_in; (void)out_size;
    const float* q    = (const float*)d_in[0];
    const float* k    = (const float*)d_in[1];
    const float* v    = (const float*)d_in[2];
    const float* bq   = (const float*)d_in[4];
    const float* bk   = (const float*)d_in[6];
    const float* bv   = (const float*)d_in[8];
    const float* bo   = (const float*)d_in[10];
    const float* rtab = (const float*)d_in[11];
    const float* g1   = (const float*)d_in[12];
    const float* b1n  = (const float*)d_in[13];
    const float* b1m  = (const float*)d_in[15];
    const float* b2m  = (const float*)d_in[17];
    const float* g2   = (const float*)d_in[18];
    const float* b2n  = (const float*)d_in[19];
    const int*   ridx = (const int*)d_in[20];
    const float* msk  = (const float*)d_in[21];
    float* out = (float*)d_out;
    char*  base = (char*)d_ws;

    float* resid = (float*)(base + O_RESID);
    short* Gp    = (short*)(base + O_GP);
    short* QF    = (short*)(base + O_QF);
    short* KF    = (short*)(base + O_KF);
    short* VF    = (short*)(base + O_VF);
    short* biasM = (short*)(base + O_BIAS);
    short* maskM = (short*)(base + O_MASK);
    short* CTXp  = (short*)(base + O_CTXP);
    float* proj1 = (float*)(base + O_PROJ1);
    float* attnb = (float*)(base + O_ATTNB);
    short* ATTp  = (short*)(base + O_ATTP);
    short* H1p   = (short*)(base + O_H1P);
    float* h2    = (float*)(base + O_H2);
    short* WT = (short*)d_out;   // weight panels in d_out; overwritten at end

    if (ws_size < (size_t)WS_NEED) return;

    k_wprep2<<<dim3(WT_TOTAL / 256), dim3(256), 0, stream>>>(
        (const float*)d_in[3], (const float*)d_in[5], (const float*)d_in[7],
        (const float*)d_in[9], (const float*)d_in[14], (const float*)d_in[16], WT);
    k_gather<<<dim3(TB16), dim3(256), 0, stream>>>(q, k, v, Gp, resid);
    k_tab2<<<dim3(NHH * 2 * QPAD * KPAD / 256), dim3(256), 0, stream>>>(rtab, ridx, biasM);
    k_maskpad2<<<dim3(NWW * QPAD * KPAD / 256), dim3(256), 0, stream>>>(msk, maskM);

    mgemm2<128, 256, 128, 2, 256, 1><<<dim3(TT / 128, 1, 3), dim3(512), 0, stream>>>(
        Gp, nullptr, WT + WT_OQ, WT + WT_TOTAL + WT_OQ,
        bq, bk, bv, QF, KF, VF);

    k_attn2<<<dim3(NHH, BNN), dim3(448), 0, stream>>>(QF, KF, VF, biasM, maskM, CTXp);

    mgemm2<256, 128, 256, 1, 128, 0><<<dim3(TT / 256, 1, 1), dim3(512), 0, stream>>>(
        CTXp, nullptr, WT + WT_OO, WT + WT_TOTAL + WT_OO,
        bo, bo, bo, proj1, nullptr, nullptr);

    k_ln_panel<<<dim3(TB16), dim3(256), 0, stream>>>(proj1, g1, b1n, resid, attnb, ATTp);

    mgemm2<256, 128, 128, 2, 384, 2><<<dim3(TT / 256, 3, 1), dim3(512), 0, stream>>>(
        ATTp, ATTp + ATT_PL, WT + WT_O1, WT + WT_TOTAL + WT_O1,
        b1m, b1m, b1m, H1p, nullptr, nullptr);

    mgemm2<256, 128, 384, 1, 128, 0><<<dim3(TT / 256, 1, 1), dim3(512), 0, stream>>>(
        H1p, nullptr, WT + WT_O2, WT + WT_TOTAL + WT_O2,
        b2m, b2m, b2m, h2, nullptr, nullptr);

    k_ln2_scatter<<<dim3(TT / 4), dim3(256), 0, stream>>>(h2, g2, b2n, attnb, out);
}